// Round 4
// baseline (198.583 us; speedup 1.0000x reference)
//
#include <hip/hip_runtime.h>
#include <math.h>

#define BDIM 64
#define HDIM 512
#define WDIM 512
#define KW   31
#define PAD  15
#define INV_KK (1.0f / 961.0f)
#define TH   8                        // output rows per wave-tile
#define SW   256                      // strip width (2 strips per row)
#define NPIX ((size_t)BDIM * HDIM * WDIM)

// acc[0]: bce sum; acc[1..64]: inter[b]; acc[65..128]: union[b]
#define NACC 129

__global__ void zero_acc_kernel(double* acc) {
    int i = threadIdx.x;
    if (i < NACC) acc[i] = 0.0;
}

// ---- DPP helpers: VALU cross-lane (no LDS pipe) -------------------------
template<int CTRL, int RMASK>
__device__ __forceinline__ float dpp_add(float p) {
    int t = __builtin_amdgcn_update_dpp(0, __builtin_bit_cast(int, p),
                                        CTRL, RMASK, 0xf, true);
    return p + __builtin_bit_cast(float, t);
}

// inclusive prefix sum over 64 lanes
__device__ __forceinline__ float wave_iscan(float p) {
    p = dpp_add<0x111, 0xf>(p);   // row_shr:1
    p = dpp_add<0x112, 0xf>(p);   // row_shr:2
    p = dpp_add<0x114, 0xf>(p);   // row_shr:4
    p = dpp_add<0x118, 0xf>(p);   // row_shr:8
    p = dpp_add<0x142, 0xa>(p);   // row_bcast:15 -> rows 1,3
    p = dpp_add<0x143, 0xc>(p);   // row_bcast:31 -> rows 2,3
    return p;
}

// inclusive prefix over first 8 lanes (within a 16-lane DPP row)
__device__ __forceinline__ float wave_iscan8(float p) {
    p = dpp_add<0x111, 0xf>(p);
    p = dpp_add<0x112, 0xf>(p);
    p = dpp_add<0x114, 0xf>(p);
    return p;
}

__device__ __forceinline__ float bperm(int idx, float v) {
    return __builtin_bit_cast(float,
        __builtin_amdgcn_ds_bpermute(idx, __builtin_bit_cast(int, v)));
}

// Vertical-first separable box, 4 columns per thread (float4), scan amortized.
// One WAVE per (image, strip sx in {0,1}, 8-row tile). Lane l owns output cols
// oc = W0+4l..+3. vsA (float4) = running 31-row vertical sums of cols
// W0-16+4l..+3 (covers strip + left halo); vsB on lanes 0..7 covers the right
// halo cols W0+240..W0+271. Per emit row: one in-lane prefix + ONE 6-DPP wave
// scan (+3-DPP halo scan) serves all 4 outputs; per output just 2 bpermutes +
// select + sub. hs(c)=P(c+15)-P(c-16) with P = global inclusive prefix of the
// 288 loaded columns:
//   low  end: own PA[j]                     (in-register, no shuffle)
//   high end: PA[(j+3)&3] from lane l+7 (j=0) / l+8 (j>=1); for lanes >=57
//             (j=0) / >=56 (j>=1) it falls in the halo: PB[(j+3)&3] from lane
//             l-57 / l-56. Both fetched, cndmask-selected.
__global__ __launch_bounds__(256, 6)
void fused_kernel(const float* __restrict__ pred,
                  const float* __restrict__ mask,
                  double* __restrict__ acc) {
    __shared__ float red[3][4];

    const int b    = blockIdx.x;
    const int lane = threadIdx.x & 63;
    const int wv   = threadIdx.x >> 6;
    const int task = blockIdx.y * 4 + wv;     // 0..127
    const int sx   = task & 1;                // strip
    const int y0   = (task >> 1) * TH;        // tile top output row
    const int W0   = sx * SW;

    const float* mbase = mask + (size_t)b * HDIM * WDIM;
    const float* pbase = pred + (size_t)b * HDIM * WDIM;

    const int acol = W0 - 16 + 4 * lane;       // A group base col (W0-16..W0+239)
    const int bcol = W0 + SW - 16 + 4 * lane;  // B group base col (lanes 0..7)
    const int oc   = W0 + 4 * lane;            // output cols oc..oc+3
    const bool a_ok = (acol >= 0);             // right side always in-bounds
    const bool b_ok = (lane < 8) && (bcol < WDIM);

    // bpermute byte-offset index registers (computed once)
    const int iA7 = ((lane + 7)  & 63) << 2;
    const int iA8 = ((lane + 8)  & 63) << 2;
    const int iB0 = ((lane - 57) & 63) << 2;
    const int iB1 = ((lane - 56) & 63) << 2;
    const bool useB0 = (lane >= 57);   // j==0 high end in halo
    const bool useB1 = (lane >= 56);   // j>=1 high end in halo

    const int tw0  = y0 - PAD;                 // first warmup row
    const int smax = (tw0 > 0) ? tw0 : 0;      // earliest legally-subtracted row

    float4 vsA = make_float4(0.f, 0.f, 0.f, 0.f);
    float4 vsB = make_float4(0.f, 0.f, 0.f, 0.f);
    float bce_acc = 0.f, inter_acc = 0.f, uni_acc = 0.f;

    auto ld_AB = [&](int row, float4& A, float4& B) {
        A = make_float4(0.f, 0.f, 0.f, 0.f);
        B = make_float4(0.f, 0.f, 0.f, 0.f);
        if (row >= 0 && row < HDIM) {          // wave-uniform
            const float* rp = mbase + (size_t)row * WDIM;
            if (a_ok) A = *reinterpret_cast<const float4*>(rp + acol);
            if (b_ok) B = *reinterpret_cast<const float4*>(rp + bcol);
        }
    };
    auto ld_S = [&](int row, float4& S, float4& T) {
        S = make_float4(0.f, 0.f, 0.f, 0.f);
        T = make_float4(0.f, 0.f, 0.f, 0.f);
        if (row >= smax) {                     // wave-uniform (row < HDIM implied)
            const float* rp = mbase + (size_t)row * WDIM;
            if (a_ok) S = *reinterpret_cast<const float4*>(rp + acol);
            if (b_ok) T = *reinterpret_cast<const float4*>(rp + bcol);
        }
    };
    auto ld_P = [&](int yo, float4& Pv) {
        Pv = make_float4(0.f, 0.f, 0.f, 0.f);
        if (yo < HDIM)                         // prefetch-past-end guard
            Pv = *reinterpret_cast<const float4*>(pbase + (size_t)yo * WDIM + oc);
    };
    auto ld_M = [&](int yo, float4& Mv) {
        Mv = *reinterpret_cast<const float4*>(mbase + (size_t)yo * WDIM + oc);
    };

    auto emit1 = [&](float hs, float M, float P) {
        const float box  = hs * INV_KK;
        const float weit = 1.f + 5.f * fabsf(box - M);
        const float e1   = __expf(-fabsf(P));
        const float bce  = fmaxf(P, 0.f) - P * M + __logf(1.f + e1);
        const float rr   = __builtin_amdgcn_rcpf(1.f + e1);
        const float sp   = (P >= 0.f) ? rr : e1 * rr;    // sigmoid from e1
        bce_acc   += bce;
        inter_acc += sp * M * weit;
        uni_acc   += (sp + M) * weit;
    };

    // ---- prologue: prime warmup halo + first pred row (cold HBM, deep cover)
    float4 cA, cB, nP;
    ld_AB(tw0, cA, cB);
    ld_P(y0, nP);

    // ---- warmup: add rows y0-15 .. y0+14 (30 rows) ----
#pragma unroll 1
    for (int i = 0; i < 30; ++i) {
        float4 nA, nB;
        ld_AB(tw0 + i + 1, nA, nB);
        vsA.x += cA.x; vsA.y += cA.y; vsA.z += cA.z; vsA.w += cA.w;
        vsB.x += cB.x; vsB.y += cB.y; vsB.z += cB.z; vsB.w += cB.w;
        cA = nA; cB = nB;
    }
    // cA/cB now hold row y0+15 (first emit add-row)

    // ---- emit: rows t = y0+15 .. y0+22 -> outputs yo = y0 .. y0+7 ----
#pragma unroll 1
    for (int i = 0; i < TH; ++i) {
        const int t  = y0 + PAD + i;
        const int yo = y0 + i;

        const float4 cP = nP;
        ld_P(yo + 1, nP);                       // next pred row (cold stream)
        float4 sA4, sB4, M4;
        ld_S(t - KW, sA4, sB4);                 // L2-warm re-read
        ld_M(yo, M4);                           // L1/L2-warm
        const float4 tA = cA, tB = cB;
        ld_AB(t + 1, cA, cB);                   // next add-row

        // slide vertical window
        vsA.x += tA.x - sA4.x; vsA.y += tA.y - sA4.y;
        vsA.z += tA.z - sA4.z; vsA.w += tA.w - sA4.w;
        vsB.x += tB.x - sB4.x; vsB.y += tB.y - sB4.y;
        vsB.z += tB.z - sB4.z; vsB.w += tB.w - sB4.w;

        // in-lane prefixes
        const float pA0 = vsA.x, pA1 = pA0 + vsA.y,
                    pA2 = pA1 + vsA.z, pA3 = pA2 + vsA.w;
        const float pB0 = vsB.x, pB1 = pB0 + vsB.y,
                    pB2 = pB1 + vsB.z, pB3 = pB2 + vsB.w;

        // wave scan of A lane-sums -> global prefixes PA[m] at positions 4l+m
        const float SA  = wave_iscan(pA3);
        const float Aex = SA - pA3;
        const float PA0 = Aex + pA0, PA1 = Aex + pA1,
                    PA2 = Aex + pA2, PA3 = SA;
        const float Atot = __builtin_bit_cast(float,
            __builtin_amdgcn_readlane(__builtin_bit_cast(int, SA), 63));

        // 8-lane halo scan (lanes 0..7) -> global prefixes PB[m]
        const float SB  = wave_iscan8(pB3);
        const float Bex = Atot + (SB - pB3);
        const float PB0 = Bex + pB0, PB1 = Bex + pB1,
                    PB2 = Bex + pB2, PB3 = Bex + pB3;

        // high-end fetches: elem (j+3)&3 from lane l+7/l+8 (or halo lane)
        const float hA0 = bperm(iA7, PA3), hB0 = bperm(iB0, PB3);
        const float hA1 = bperm(iA8, PA0), hB1 = bperm(iB1, PB0);
        const float hA2 = bperm(iA8, PA1), hB2 = bperm(iB1, PB1);
        const float hA3 = bperm(iA8, PA2), hB3 = bperm(iB1, PB2);

        const float hs0 = (useB0 ? hB0 : hA0) - PA0;
        const float hs1 = (useB1 ? hB1 : hA1) - PA1;
        const float hs2 = (useB1 ? hB2 : hA2) - PA2;
        const float hs3 = (useB1 ? hB3 : hA3) - PA3;

        emit1(hs0, M4.x, cP.x);
        emit1(hs1, M4.y, cP.y);
        emit1(hs2, M4.z, cP.z);
        emit1(hs3, M4.w, cP.w);
    }

    // ---- block reduction (4 waves) ----
#pragma unroll
    for (int off = 32; off > 0; off >>= 1) {
        bce_acc   += __shfl_down(bce_acc, off);
        inter_acc += __shfl_down(inter_acc, off);
        uni_acc   += __shfl_down(uni_acc, off);
    }
    if (lane == 0) {
        red[0][wv] = bce_acc;
        red[1][wv] = inter_acc;
        red[2][wv] = uni_acc;
    }
    __syncthreads();
    if (threadIdx.x == 0) {
        float bs = 0.f, is = 0.f, us = 0.f;
#pragma unroll
        for (int w = 0; w < 4; ++w) { bs += red[0][w]; is += red[1][w]; us += red[2][w]; }
        atomicAdd(&acc[0],      (double)bs);
        atomicAdd(&acc[1 + b],  (double)is);
        atomicAdd(&acc[65 + b], (double)us);
    }
}

__global__ void finalize_kernel(const double* __restrict__ acc, float* __restrict__ out) {
    const int b = threadIdx.x;   // one wave
    double inter = acc[1 + b];
    double uni   = acc[65 + b];
    double wiou  = 1.0 - (inter + 1.0) / (uni - inter + 1.0);
#pragma unroll
    for (int off = 32; off > 0; off >>= 1) wiou += __shfl_down(wiou, off);
    if (b == 0) {
        double wbce = acc[0] / (double)NPIX;
        out[0] = (float)(wbce + wiou / (double)BDIM);
    }
}

extern "C" void kernel_launch(void* const* d_in, const int* in_sizes, int n_in,
                              void* d_out, int out_size, void* d_ws, size_t ws_size,
                              hipStream_t stream) {
    const float* pred = (const float*)d_in[0];
    const float* mask = (const float*)d_in[1];
    float* out = (float*)d_out;
    double* acc = (double*)d_ws;

    zero_acc_kernel<<<1, 256, 0, stream>>>(acc);

    dim3 grid(BDIM, (HDIM / TH) * 2 / 4);   // 64 x 32 blocks, 4 waves each
    fused_kernel<<<grid, 256, 0, stream>>>(pred, mask, acc);

    finalize_kernel<<<1, 64, 0, stream>>>(acc, out);
}